// Round 2
// baseline (1139.385 us; speedup 1.0000x reference)
//
#include <hip/hip_runtime.h>
#include <hip/hip_bf16.h>
#include <stdint.h>

typedef __attribute__((ext_vector_type(8))) short bf16x8;
typedef __attribute__((ext_vector_type(4))) float f32x4;
typedef __attribute__((ext_vector_type(4))) unsigned short us4;

#define T_TOK 8192
#define DDIM 1024
#define FDIM 4096
#define F2DIM 2048
#define NEXP 8

__device__ __forceinline__ unsigned short f2bf(float f) {
    unsigned u = __float_as_uint(f);
    u += 0x7fffu + ((u >> 16) & 1u);
    return (unsigned short)(u >> 16);
}
__device__ __forceinline__ float bf2f(unsigned short h) {
    return __uint_as_float(((unsigned)h) << 16);
}

// async global->LDS, 16B per lane. LDS dest is wave-uniform base + lane*16.
__device__ __forceinline__ void gl2lds16(const void* g, void* l) {
    __builtin_amdgcn_global_load_lds(
        (const __attribute__((address_space(1))) unsigned int*)(unsigned long long)g,
        (__attribute__((address_space(3))) unsigned int*)(unsigned int)(unsigned long long)l,
        16, 0, 0);
}

// ---------------- router: logits -> softmax top2 (renormalized) ----------------
__global__ void k_router(const float* __restrict__ x, const float* __restrict__ rw,
                         const float* __restrict__ rb, int* __restrict__ eid,
                         float* __restrict__ ewt, int* __restrict__ cnt) {
    const int wid = threadIdx.x >> 6, lane = threadIdx.x & 63;
    const int t = blockIdx.x * 4 + wid;
    float acc[8];
#pragma unroll
    for (int e = 0; e < 8; ++e) acc[e] = 0.f;
    const float4* xr = (const float4*)(x + (long long)t * DDIM);
#pragma unroll
    for (int c = 0; c < 4; ++c) {
        float4 xv = xr[lane + 64 * c];
        int d0 = (lane + 64 * c) * 4;
        float xs[4] = {xv.x, xv.y, xv.z, xv.w};
#pragma unroll
        for (int j = 0; j < 4; ++j) {
            const float* wrow = rw + (long long)(d0 + j) * 8;
#pragma unroll
            for (int e = 0; e < 8; ++e) acc[e] += xs[j] * wrow[e];
        }
    }
#pragma unroll
    for (int off = 32; off; off >>= 1)
#pragma unroll
        for (int e = 0; e < 8; ++e) acc[e] += __shfl_xor(acc[e], off);
    if (lane == 0) {
        float lg[8];
#pragma unroll
        for (int e = 0; e < 8; ++e) lg[e] = acc[e] + rb[e];
        int e0 = 0;
#pragma unroll
        for (int e = 1; e < 8; ++e) if (lg[e] > lg[e0]) e0 = e;
        int e1 = -1;
#pragma unroll
        for (int e = 0; e < 8; ++e) {
            if (e == e0) continue;
            if (e1 < 0 || lg[e] > lg[e1]) e1 = e;
        }
        float w0 = 1.f / (1.f + expf(lg[e1] - lg[e0]));
        eid[2 * t] = e0; eid[2 * t + 1] = e1;
        ewt[2 * t] = w0; ewt[2 * t + 1] = 1.f - w0;
        atomicAdd(&cnt[e0], 1);
        atomicAdd(&cnt[e1], 1);
    }
}

__global__ void k_scan(const int* __restrict__ cnt, int* __restrict__ offs,
                       int* __restrict__ cursor) {
    if (threadIdx.x == 0) {
        int s = 0;
        for (int e = 0; e < NEXP; ++e) { offs[e] = s; cursor[e] = s; s += cnt[e]; }
        offs[NEXP] = s;
    }
}

__global__ void k_scatter(const int* __restrict__ eid, const float* __restrict__ ewt,
                          int* __restrict__ cursor, int* __restrict__ rowtok,
                          float* __restrict__ roww) {
    int t = blockIdx.x * blockDim.x + threadIdx.x;
#pragma unroll
    for (int k = 0; k < 2; ++k) {
        int e = eid[2 * t + k];
        int p = atomicAdd(&cursor[e], 1);
        rowtok[p] = (t << 1) | k;
        roww[p] = ewt[2 * t + k];
    }
}

// ---------------- f32 -> bf16 convert (same layout) ----------------
__global__ void k_cvt(const float* __restrict__ in, unsigned short* __restrict__ out,
                      long long n4) {
    long long i = (long long)blockIdx.x * blockDim.x + threadIdx.x;
    long long stride = (long long)gridDim.x * blockDim.x;
    for (; i < n4; i += stride) {
        float4 v = ((const float4*)in)[i];
        us4 o;
        o.x = f2bf(v.x); o.y = f2bf(v.y); o.z = f2bf(v.z); o.w = f2bf(v.w);
        ((us4*)out)[i] = o;
    }
}

// ------- transpose+convert: in [R][C] f32 -> out [C][R] bf16, 64r x 32c tiles --
__global__ void k_tp2(const float* __restrict__ in, unsigned short* __restrict__ out,
                      int R, int C) {
    const long long base = (long long)blockIdx.z * R * C;
    __shared__ unsigned short ts[32][72];
    const int c0 = blockIdx.x * 32, r0 = blockIdx.y * 64;
    const int ci = threadIdx.x & 31, ri = threadIdx.x >> 5;
#pragma unroll
    for (int rr = 0; rr < 8; ++rr) {
        int r = r0 + rr * 8 + ri;
        ts[ci][rr * 8 + ri] = f2bf(in[base + (long long)r * C + c0 + ci]);
    }
    __syncthreads();
    const int oc = threadIdx.x >> 3, l = threadIdx.x & 7;
    uint4 v4 = *(const uint4*)&ts[oc][l * 8];
    *(uint4*)(out + base + (long long)(c0 + oc) * R + r0 + l * 8) = v4;
}

// ---------------- grouped GEMM: 256x256 tile, BK=32, counted-vmcnt pipeline ----
// C[M,N] = A[M,K] @ Bt[N,K]^T ; 512 thr = 8 waves (2M x 4N), wave tile 128x64.
// LDS 64KB: As[2][256][32], Bs[2][256][32] bf16, XOR-swizzled 16B chunks
// (source-side pre-swizzle, read-side same XOR: slot = c ^ ((row>>1)&3)).
// MODE 0: A gathered via rowtok -> gelu((acc+b1)*gate) -> hbuf
// MODE 1: A compact rows -> (acc+b2)*roww scatter -> ybuf[slot][tok]
// MODE 2: A direct -> gelu((acc+sb1)*sgate) -> hs
// MODE 3: A direct -> (acc+sb2)*sigmoid(sw) -> ysh
template <int MODE>
__launch_bounds__(512, 2)
__global__ void k_gemm(const short* __restrict__ A, const short* __restrict__ Bt,
                       const float* __restrict__ bias, const float* __restrict__ gatev,
                       unsigned short* __restrict__ outb, const int* __restrict__ cnt,
                       const int* __restrict__ offs, const int* __restrict__ rowtok,
                       const float* __restrict__ roww, const float* __restrict__ swp,
                       int Kd, int Ncols, long long btStride, int biasStride) {
    const int e = blockIdx.z;
    int M, oE;
    if (MODE <= 1) { M = cnt[e]; oE = offs[e]; }
    else { M = T_TOK; oE = 0; }
    const int tm = blockIdx.y, tn = blockIdx.x;
    if (tm * 256 >= M) return;

    __shared__ short As[2][256][32];
    __shared__ short Bs[2][256][32];

    const int tid = threadIdx.x, w = tid >> 6, lane = tid & 63;
    const int fr = lane & 15, fg = lane >> 4;
    const int wr = w >> 2, wc = w & 3;

    // ---- staging setup: chunk id = tid + i*512; row=id>>2, slot=id&3 ----
    const short *agp0, *agp1, *bgp0, *bgp1;
    {
        int id = tid, row = id >> 2;
        int gc = (id & 3) ^ ((row >> 1) & 3);
        int r = tm * 256 + row; if (r > M - 1) r = M - 1;
        long long rowix = (MODE == 0) ? (long long)(rowtok[oE + r] >> 1)
                        : (MODE == 1) ? (long long)(oE + r) : (long long)r;
        agp0 = A + rowix * (long long)Kd + gc * 8;
        int n = tn * 256 + row;
        bgp0 = Bt + (long long)e * btStride + (long long)n * Kd + gc * 8;
    }
    {
        int id = tid + 512, row = id >> 2;
        int gc = (id & 3) ^ ((row >> 1) & 3);
        int r = tm * 256 + row; if (r > M - 1) r = M - 1;
        long long rowix = (MODE == 0) ? (long long)(rowtok[oE + r] >> 1)
                        : (MODE == 1) ? (long long)(oE + r) : (long long)r;
        agp1 = A + rowix * (long long)Kd + gc * 8;
        int n = tn * 256 + row;
        bgp1 = Bt + (long long)e * btStride + (long long)n * Kd + gc * 8;
    }
    short* const as_base = &As[0][0][0];
    short* const bs_base = &Bs[0][0][0];
    const int wofs0 = (w * 64) * 8, wofs1 = (w * 64 + 512) * 8;   // shorts

    auto STAGE = [&](int b) {
        short* ab = as_base + b * 8192;
        short* bb = bs_base + b * 8192;
        gl2lds16(agp0, ab + wofs0);
        gl2lds16(agp1, ab + wofs1);
        gl2lds16(bgp0, bb + wofs0);
        gl2lds16(bgp1, bb + wofs1);
        agp0 += 32; agp1 += 32; bgp0 += 32; bgp1 += 32;
    };

    f32x4 acc[8][4];
#pragma unroll
    for (int m = 0; m < 8; ++m)
#pragma unroll
        for (int n = 0; n < 4; ++n)
            acc[m][n] = (f32x4){0.f, 0.f, 0.f, 0.f};

    const int slot = fg ^ ((fr >> 1) & 3);
    const int arow0 = wr * 128 + fr;     // + m*16
    const int brow0 = wc * 64 + fr;      // + n*16
    const int nk = Kd / 32;

    STAGE(0);
    for (int t = 0; t < nk; ++t) {
        const int cur = t & 1;
        if (t + 1 < nk) {
            STAGE(cur ^ 1);
            asm volatile("s_waitcnt vmcnt(4)" ::: "memory");
        } else {
            asm volatile("s_waitcnt vmcnt(0)" ::: "memory");
        }
        __builtin_amdgcn_s_barrier();
        asm volatile("" ::: "memory");

        const short* Ab = as_base + cur * 8192;
        const short* Bb = bs_base + cur * 8192;
        bf16x8 a[8], b[4];
#pragma unroll
        for (int m = 0; m < 8; ++m)
            a[m] = *(const bf16x8*)(Ab + (arow0 + m * 16) * 32 + slot * 8);
#pragma unroll
        for (int n = 0; n < 4; ++n)
            b[n] = *(const bf16x8*)(Bb + (brow0 + n * 16) * 32 + slot * 8);

        __builtin_amdgcn_s_setprio(1);
#pragma unroll
        for (int m = 0; m < 8; ++m)
#pragma unroll
            for (int n = 0; n < 4; ++n)
                acc[m][n] = __builtin_amdgcn_mfma_f32_16x16x32_bf16(a[m], b[n], acc[m][n], 0, 0, 0);
        __builtin_amdgcn_s_setprio(0);

        asm volatile("" ::: "memory");
        __builtin_amdgcn_s_barrier();
        asm volatile("" ::: "memory");
    }

    // ---- epilogue. C/D layout: col=lane&15, row=(lane>>4)*4+i ----
    const int mrow0 = tm * 256 + wr * 128;
    const int col0 = tn * 256 + wc * 64;
    const int biasOff = e * biasStride;

    if (MODE == 0 || MODE == 2) {
#pragma unroll
        for (int n = 0; n < 4; ++n) {
            int col = col0 + n * 16 + fr;
            float bv = bias[biasOff + col];
            float gv = gatev[biasOff + col];
#pragma unroll
            for (int m = 0; m < 8; ++m) {
#pragma unroll
                for (int i = 0; i < 4; ++i) {
                    int grow = mrow0 + m * 16 + fg * 4 + i;
                    if (grow < M) {
                        float v = (acc[m][n][i] + bv) * gv;
                        float h = 0.5f * v * (1.0f + erff(v * 0.70710678118654752f));
                        outb[(long long)(oE + grow) * Ncols + col] = f2bf(h);
                    }
                }
            }
        }
    } else if (MODE == 1) {
#pragma unroll
        for (int n = 0; n < 4; ++n) {
            int col = col0 + n * 16 + fr;
            float bv = bias[biasOff + col];
#pragma unroll
            for (int m = 0; m < 8; ++m) {
#pragma unroll
                for (int i = 0; i < 4; ++i) {
                    int grow = mrow0 + m * 16 + fg * 4 + i;
                    if (grow < M) {
                        int ent = rowtok[oE + grow];
                        float wv = roww[oE + grow];
                        int tok = ent >> 1, slt = ent & 1;
                        float v = (acc[m][n][i] + bv) * wv;
                        outb[((long long)slt * T_TOK + tok) * DDIM + col] = f2bf(v);
                    }
                }
            }
        }
    } else {
        float sigw = 1.f / (1.f + expf(-swp[0]));
#pragma unroll
        for (int n = 0; n < 4; ++n) {
            int col = col0 + n * 16 + fr;
            float bv = bias[col];
#pragma unroll
            for (int m = 0; m < 8; ++m) {
#pragma unroll
                for (int i = 0; i < 4; ++i) {
                    int grow = mrow0 + m * 16 + fg * 4 + i;
                    if (grow < M) {
                        float v = (acc[m][n][i] + bv) * sigw;
                        outb[(long long)grow * Ncols + col] = f2bf(v);
                    }
                }
            }
        }
    }
}

// ---------------- final: y = y0+y1+ysh ; LayerNorm over D ----------------
__global__ void k_ln(const unsigned short* __restrict__ y0,
                     const unsigned short* __restrict__ y1,
                     const unsigned short* __restrict__ ysh,
                     const float* __restrict__ g, const float* __restrict__ b,
                     float* __restrict__ out) {
    const int wid = threadIdx.x >> 6, lane = threadIdx.x & 63;
    const long long t = (long long)blockIdx.x * 4 + wid;
    const long long base = t * DDIM;
    float v[16];
    float s = 0.f, sq = 0.f;
#pragma unroll
    for (int j = 0; j < 2; ++j) {
        int c0 = (lane + 64 * j) * 8;
        uint4 a0 = *(const uint4*)(y0 + base + c0);
        uint4 a1 = *(const uint4*)(y1 + base + c0);
        uint4 a2 = *(const uint4*)(ysh + base + c0);
        const unsigned* u0 = (const unsigned*)&a0;
        const unsigned* u1 = (const unsigned*)&a1;
        const unsigned* u2 = (const unsigned*)&a2;
#pragma unroll
        for (int q = 0; q < 4; ++q) {
            float lo = bf2f((unsigned short)u0[q]) + bf2f((unsigned short)u1[q]) +
                       bf2f((unsigned short)u2[q]);
            float hi = bf2f((unsigned short)(u0[q] >> 16)) + bf2f((unsigned short)(u1[q] >> 16)) +
                       bf2f((unsigned short)(u2[q] >> 16));
            v[j * 8 + q * 2] = lo;
            v[j * 8 + q * 2 + 1] = hi;
            s += lo + hi;
            sq += lo * lo + hi * hi;
        }
    }
#pragma unroll
    for (int off = 32; off; off >>= 1) {
        s += __shfl_xor(s, off);
        sq += __shfl_xor(sq, off);
    }
    const float mean = s * (1.f / DDIM);
    const float var = sq * (1.f / DDIM) - mean * mean;
    const float inv = rsqrtf(var + 1e-5f);
#pragma unroll
    for (int j = 0; j < 2; ++j) {
        int c0 = (lane + 64 * j) * 8;
#pragma unroll
        for (int h = 0; h < 2; ++h) {
            float4 o4;
            float* op = (float*)&o4;
#pragma unroll
            for (int q = 0; q < 4; ++q) {
                int k = h * 4 + q;
                int col = c0 + k;
                op[q] = (v[j * 8 + k] - mean) * inv * g[col] + b[col];
            }
            *(float4*)(out + base + c0 + h * 4) = o4;
        }
    }
}

extern "C" void kernel_launch(void* const* d_in, const int* in_sizes, int n_in,
                              void* d_out, int out_size, void* d_ws, size_t ws_size,
                              hipStream_t stream) {
    const float* x    = (const float*)d_in[0];
    const float* rw   = (const float*)d_in[1];
    const float* rb   = (const float*)d_in[2];
    const float* w1   = (const float*)d_in[3];
    const float* b1   = (const float*)d_in[4];
    const float* gate = (const float*)d_in[5];
    const float* w2   = (const float*)d_in[6];
    const float* b2   = (const float*)d_in[7];
    const float* sw1  = (const float*)d_in[8];
    const float* sb1  = (const float*)d_in[9];
    const float* sgate= (const float*)d_in[10];
    const float* sw2  = (const float*)d_in[11];
    const float* sb2  = (const float*)d_in[12];
    const float* swt  = (const float*)d_in[13];
    const float* lng  = (const float*)d_in[14];
    const float* lnb  = (const float*)d_in[15];
    float* out = (float*)d_out;

    char* p = (char*)d_ws;
    auto take = [&](size_t n) { char* r = p; p += (n + 255) & ~(size_t)255; return r; };
    short* xb   = (short*)take((size_t)T_TOK * DDIM * 2);
    short* w1t  = (short*)take((size_t)NEXP * FDIM * DDIM * 2);
    short* w2t  = (short*)take((size_t)NEXP * DDIM * FDIM * 2);
    short* sw1t = (short*)take((size_t)F2DIM * DDIM * 2);
    short* sw2t = (short*)take((size_t)DDIM * F2DIM * 2);
    short* hbuf = (short*)take((size_t)2 * T_TOK * FDIM * 2);
    short* hs   = (short*)take((size_t)T_TOK * F2DIM * 2);
    unsigned short* ybuf = (unsigned short*)take((size_t)2 * T_TOK * DDIM * 2);
    unsigned short* ysh  = (unsigned short*)take((size_t)T_TOK * DDIM * 2);
    int* eid    = (int*)take((size_t)T_TOK * 2 * 4);
    float* ewt  = (float*)take((size_t)T_TOK * 2 * 4);
    int* rowtok = (int*)take((size_t)2 * T_TOK * 4);
    float* roww = (float*)take((size_t)2 * T_TOK * 4);
    int* cnt    = (int*)take(64);
    int* offs   = (int*)take(64);
    int* cursor = (int*)take(64);

    hipMemsetAsync(cnt, 0, NEXP * sizeof(int), stream);
    k_router<<<T_TOK / 4, 256, 0, stream>>>(x, rw, rb, eid, ewt, cnt);
    k_scan<<<1, 64, 0, stream>>>(cnt, offs, cursor);
    k_scatter<<<T_TOK / 256, 256, 0, stream>>>(eid, ewt, cursor, rowtok, roww);

    k_cvt<<<2048, 256, 0, stream>>>(x, (unsigned short*)xb, (long long)T_TOK * DDIM / 4);
    k_tp2<<<dim3(FDIM / 32, DDIM / 64, NEXP), 256, 0, stream>>>(w1, (unsigned short*)w1t, DDIM, FDIM);
    k_tp2<<<dim3(DDIM / 32, FDIM / 64, NEXP), 256, 0, stream>>>(w2, (unsigned short*)w2t, FDIM, DDIM);
    k_tp2<<<dim3(F2DIM / 32, DDIM / 64, 1), 256, 0, stream>>>(sw1, (unsigned short*)sw1t, DDIM, F2DIM);
    k_tp2<<<dim3(DDIM / 32, F2DIM / 64, 1), 256, 0, stream>>>(sw2, (unsigned short*)sw2t, F2DIM, DDIM);

    // fc1 moe: [rows,1024] @ w1t[e][4096,1024]^T -> hbuf [rows,4096]
    k_gemm<0><<<dim3(FDIM / 256, 64, NEXP), 512, 0, stream>>>(
        xb, w1t, b1, gate, (unsigned short*)hbuf, cnt, offs, rowtok, roww, swt,
        DDIM, FDIM, (long long)FDIM * DDIM, FDIM);
    // fc2 moe: hbuf [rows,4096] @ w2t[e][1024,4096]^T -> ybuf slots
    k_gemm<1><<<dim3(DDIM / 256, 64, NEXP), 512, 0, stream>>>(
        hbuf, w2t, b2, gate, ybuf, cnt, offs, rowtok, roww, swt,
        FDIM, DDIM, (long long)DDIM * FDIM, DDIM);
    // shared fc1: xb [8192,1024] @ sw1t[2048,1024]^T -> hs
    k_gemm<2><<<dim3(F2DIM / 256, T_TOK / 256, 1), 512, 0, stream>>>(
        xb, sw1t, sb1, sgate, (unsigned short*)hs, cnt, offs, rowtok, roww, swt,
        DDIM, F2DIM, 0, 0);
    // shared fc2: hs [8192,2048] @ sw2t[1024,2048]^T -> ysh
    k_gemm<3><<<dim3(DDIM / 256, T_TOK / 256, 1), 512, 0, stream>>>(
        hs, sw2t, sb2, sgate, ysh, cnt, offs, rowtok, roww, swt,
        F2DIM, DDIM, 0, 0);

    k_ln<<<T_TOK / 4, 256, 0, stream>>>(ybuf, ybuf + (size_t)T_TOK * DDIM, ysh, lng, lnb, out);
}

// Round 3
// 1073.426 us; speedup vs baseline: 1.0614x; 1.0614x over previous
//
#include <hip/hip_runtime.h>
#include <hip/hip_bf16.h>
#include <stdint.h>

typedef __attribute__((ext_vector_type(8))) short bf16x8;
typedef __attribute__((ext_vector_type(4))) float f32x4;
typedef __attribute__((ext_vector_type(4))) unsigned short us4;

#define T_TOK 8192
#define DDIM 1024
#define FDIM 4096
#define F2DIM 2048
#define NEXP 8

__device__ __forceinline__ unsigned short f2bf(float f) {
    unsigned u = __float_as_uint(f);
    u += 0x7fffu + ((u >> 16) & 1u);
    return (unsigned short)(u >> 16);
}
__device__ __forceinline__ float bf2f(unsigned short h) {
    return __uint_as_float(((unsigned)h) << 16);
}
__device__ __forceinline__ float gelu_fast(float v) {
    float u = 0.7978845608028654f * v * (1.0f + 0.044715f * v * v);
    float a = fabsf(u);
    float t = __expf(-2.0f * a);
    float th = (1.0f - t) / (1.0f + t);
    th = u < 0.0f ? -th : th;
    return 0.5f * v * (1.0f + th);
}

// async global->LDS, 16B per lane. LDS dest is wave-uniform base + lane*16.
__device__ __forceinline__ void gl2lds16(const void* g, void* l) {
    __builtin_amdgcn_global_load_lds(
        (const __attribute__((address_space(1))) unsigned int*)(unsigned long long)g,
        (__attribute__((address_space(3))) unsigned int*)(unsigned int)(unsigned long long)l,
        16, 0, 0);
}

// ---------------- router ----------------
__global__ void k_router(const float* __restrict__ x, const float* __restrict__ rw,
                         const float* __restrict__ rb, int* __restrict__ eid,
                         float* __restrict__ ewt, int* __restrict__ cnt) {
    const int wid = threadIdx.x >> 6, lane = threadIdx.x & 63;
    const int t = blockIdx.x * 4 + wid;
    float acc[8];
#pragma unroll
    for (int e = 0; e < 8; ++e) acc[e] = 0.f;
    const float4* xr = (const float4*)(x + (long long)t * DDIM);
#pragma unroll
    for (int c = 0; c < 4; ++c) {
        float4 xv = xr[lane + 64 * c];
        int d0 = (lane + 64 * c) * 4;
        float xs[4] = {xv.x, xv.y, xv.z, xv.w};
#pragma unroll
        for (int j = 0; j < 4; ++j) {
            const float* wrow = rw + (long long)(d0 + j) * 8;
#pragma unroll
            for (int e = 0; e < 8; ++e) acc[e] += xs[j] * wrow[e];
        }
    }
#pragma unroll
    for (int off = 32; off; off >>= 1)
#pragma unroll
        for (int e = 0; e < 8; ++e) acc[e] += __shfl_xor(acc[e], off);
    if (lane == 0) {
        float lg[8];
#pragma unroll
        for (int e = 0; e < 8; ++e) lg[e] = acc[e] + rb[e];
        int e0 = 0;
#pragma unroll
        for (int e = 1; e < 8; ++e) if (lg[e] > lg[e0]) e0 = e;
        int e1 = -1;
#pragma unroll
        for (int e = 0; e < 8; ++e) {
            if (e == e0) continue;
            if (e1 < 0 || lg[e] > lg[e1]) e1 = e;
        }
        float w0 = 1.f / (1.f + expf(lg[e1] - lg[e0]));
        eid[2 * t] = e0; eid[2 * t + 1] = e1;
        ewt[2 * t] = w0; ewt[2 * t + 1] = 1.f - w0;
        atomicAdd(&cnt[e0], 1);
        atomicAdd(&cnt[e1], 1);
    }
}

__global__ void k_scan(const int* __restrict__ cnt, int* __restrict__ offs,
                       int* __restrict__ cursor) {
    if (threadIdx.x == 0) {
        int s = 0;
        for (int e = 0; e < NEXP; ++e) { offs[e] = s; cursor[e] = s; s += cnt[e]; }
        offs[NEXP] = s;
    }
}

__global__ void k_scatter(const int* __restrict__ eid, const float* __restrict__ ewt,
                          int* __restrict__ cursor, int* __restrict__ rowtok,
                          float* __restrict__ roww) {
    int t = blockIdx.x * blockDim.x + threadIdx.x;
#pragma unroll
    for (int k = 0; k < 2; ++k) {
        int e = eid[2 * t + k];
        int p = atomicAdd(&cursor[e], 1);
        rowtok[p] = (t << 1) | k;
        roww[p] = ewt[2 * t + k];
    }
}

// ---------------- f32 -> bf16 convert ----------------
__global__ void k_cvt(const float* __restrict__ in, unsigned short* __restrict__ out,
                      long long n4) {
    long long i = (long long)blockIdx.x * blockDim.x + threadIdx.x;
    long long stride = (long long)gridDim.x * blockDim.x;
    for (; i < n4; i += stride) {
        float4 v = ((const float4*)in)[i];
        us4 o;
        o.x = f2bf(v.x); o.y = f2bf(v.y); o.z = f2bf(v.z); o.w = f2bf(v.w);
        ((us4*)out)[i] = o;
    }
}

// ------- transpose+convert: in [R][C] f32 -> out [C][R] bf16, 64r x 32c tiles --
__global__ void k_tp3(const float* __restrict__ in, unsigned short* __restrict__ out,
                      int R, int C) {
    const long long base = (long long)blockIdx.z * R * C;
    __shared__ unsigned short ts[32][80];
    const int c0 = blockIdx.x * 32, r0 = blockIdx.y * 64;
    const int t = threadIdx.x;
#pragma unroll
    for (int i = 0; i < 2; ++i) {
        int idx = t + i * 256;
        int row = idx >> 3, c4 = idx & 7;
        float4 v = *(const float4*)(in + base + (long long)(r0 + row) * C + c0 + c4 * 4);
        ts[c4 * 4 + 0][row] = f2bf(v.x);
        ts[c4 * 4 + 1][row] = f2bf(v.y);
        ts[c4 * 4 + 2][row] = f2bf(v.z);
        ts[c4 * 4 + 3][row] = f2bf(v.w);
    }
    __syncthreads();
    int c = t >> 3, r8 = t & 7;
    uint4 o = *(const uint4*)&ts[c][r8 * 8];
    *(uint4*)(out + base + (long long)(c0 + c) * R + r0 + r8 * 8) = o;
}

// ---------------- grouped GEMM, slab-pipelined 8-phase-style ----------------
// 256x256 tile, BK=64 as 2x32-k slabs; 4 rotating LDS regions per operand.
// 512 thr = 8 waves (2M x 4N), wave tile 128x64. Phase i: ds_read slab i,
// stage slab i+3, vmcnt(8) (verifies slab i+1, 3-phase lead), bar,
// lgkmcnt(0), 32 MFMA, bar. z in [0,9): z<8 = MoE expert, z==8 = shared.
template <int FC>
__launch_bounds__(512, 2)
__global__ void k_fc(const short* __restrict__ Amoe, const short* __restrict__ Ash,
                     const short* __restrict__ Bmoe, const short* __restrict__ Bsh,
                     const float* __restrict__ biasM, const float* __restrict__ biasS,
                     const float* __restrict__ gateM, const float* __restrict__ gateS,
                     unsigned short* __restrict__ outM, unsigned short* __restrict__ outS,
                     const int* __restrict__ cnt, const int* __restrict__ offs,
                     const int* __restrict__ rowtok, const float* __restrict__ roww,
                     const float* __restrict__ swp) {
    const int z = blockIdx.z;
    const bool sh = (z == 8);
    const int Kd = (FC == 1) ? 1024 : (sh ? 2048 : 4096);
    const int Ncols = (FC == 1) ? (sh ? 2048 : 4096) : 1024;
    const int M = sh ? T_TOK : cnt[z];
    const int oE = sh ? 0 : offs[z];
    const int tm = blockIdx.y, tn = blockIdx.x;
    if (tm * 256 >= M || tn * 256 >= Ncols) return;

    const short* A = sh ? Ash : Amoe;
    const short* B = sh ? Bsh
                        : Bmoe + (long long)z * ((FC == 1) ? (long long)FDIM * DDIM
                                                           : (long long)DDIM * FDIM);

    extern __shared__ short smem[];
    short* const as_base = smem;            // 4 regions x 8192 shorts (16KB)
    short* const bs_base = smem + 32768;    // 4 regions x 8192 shorts

    const int tid = threadIdx.x, w = tid >> 6, lane = tid & 63;
    const int fr = lane & 15, fg = lane >> 4;
    const int wr = w >> 2, wc = w & 3;

    // staging chunk assignment: chunk id in {tid, tid+512}; row=id>>2, c=id&3,
    // source pre-swizzle gc = c ^ ((row>>1)&3); LDS dest linear by id.
    const short *agp0, *agp1, *bgp0, *bgp1;
    {
        int id = tid, row = id >> 2;
        int gc = (id & 3) ^ ((row >> 1) & 3);
        int r = tm * 256 + row; if (r > M - 1) r = M - 1;
        long long rowix = (FC == 1) ? (sh ? (long long)r : (long long)(rowtok[oE + r] >> 1))
                                    : (sh ? (long long)r : (long long)(oE + r));
        agp0 = A + rowix * (long long)Kd + gc * 8;
        bgp0 = B + (long long)(tn * 256 + row) * Kd + gc * 8;
    }
    {
        int id = tid + 512, row = id >> 2;
        int gc = (id & 3) ^ ((row >> 1) & 3);
        int r = tm * 256 + row; if (r > M - 1) r = M - 1;
        long long rowix = (FC == 1) ? (sh ? (long long)r : (long long)(rowtok[oE + r] >> 1))
                                    : (sh ? (long long)r : (long long)(oE + r));
        agp1 = A + rowix * (long long)Kd + gc * 8;
        bgp1 = B + (long long)(tn * 256 + row) * Kd + gc * 8;
    }
    const int aofs0 = (w * 64) * 8, aofs1 = (512 + w * 64) * 8;  // shorts

    int sli = 0;  // next slab index to stage
    auto STAGE = [&]() {
        short* ar = as_base + (sli & 3) * 8192;
        short* br = bs_base + (sli & 3) * 8192;
        gl2lds16(agp0, ar + aofs0);
        gl2lds16(agp1, ar + aofs1);
        gl2lds16(bgp0, br + aofs0);
        gl2lds16(bgp1, br + aofs1);
        agp0 += 32; agp1 += 32; bgp0 += 32; bgp1 += 32;
        ++sli;
    };

    f32x4 acc[8][4];
#pragma unroll
    for (int m = 0; m < 8; ++m)
#pragma unroll
        for (int n = 0; n < 4; ++n)
            acc[m][n] = (f32x4){0.f, 0.f, 0.f, 0.f};

    const int slot = fg ^ ((fr >> 1) & 3);
    const int arow0 = wr * 128 + fr;
    const int brow0 = wc * 64 + fr;
    const int nk2 = Kd / 32;  // #slabs (>=32 in all modes)

    STAGE(); STAGE(); STAGE();
    asm volatile("s_waitcnt vmcnt(8)" ::: "memory");   // slab 0 landed
    __builtin_amdgcn_s_barrier();
    asm volatile("" ::: "memory");

    for (int i = 0; i < nk2; ++i) {
        const short* Ar = as_base + (i & 3) * 8192;
        const short* Br = bs_base + (i & 3) * 8192;
        bf16x8 a[8], b[4];
#pragma unroll
        for (int m = 0; m < 8; ++m)
            a[m] = *(const bf16x8*)(Ar + (arow0 + m * 16) * 32 + slot * 8);
#pragma unroll
        for (int n = 0; n < 4; ++n)
            b[n] = *(const bf16x8*)(Br + (brow0 + n * 16) * 32 + slot * 8);

        if (i + 3 < nk2) {
            STAGE();
            asm volatile("s_waitcnt vmcnt(8)" ::: "memory");   // slab i+1 landed
        } else if (i + 2 < nk2) {
            asm volatile("s_waitcnt vmcnt(4)" ::: "memory");
        } else if (i + 1 < nk2) {
            asm volatile("s_waitcnt vmcnt(0)" ::: "memory");
        }
        __builtin_amdgcn_s_barrier();
        asm volatile("s_waitcnt lgkmcnt(0)" ::: "memory");
        __builtin_amdgcn_sched_barrier(0);

        __builtin_amdgcn_s_setprio(1);
#pragma unroll
        for (int m = 0; m < 8; ++m)
#pragma unroll
            for (int n = 0; n < 4; ++n)
                acc[m][n] = __builtin_amdgcn_mfma_f32_16x16x32_bf16(a[m], b[n], acc[m][n], 0, 0, 0);
        __builtin_amdgcn_s_setprio(0);

        asm volatile("" ::: "memory");
        __builtin_amdgcn_s_barrier();
        asm volatile("" ::: "memory");
    }

    // ---- epilogue. C/D layout: col=lane&15, row=(lane>>4)*4+i ----
    const int mrow0 = tm * 256 + wr * 128;
    const int col0 = tn * 256 + wc * 64;

    if (FC == 1) {
        const float* bp = sh ? biasS : biasM + (long long)z * FDIM;
        const float* gp = sh ? gateS : gateM + (long long)z * FDIM;
        unsigned short* outp = sh ? outS : outM;
#pragma unroll
        for (int n = 0; n < 4; ++n) {
            int col = col0 + n * 16 + fr;
            float bv = bp[col];
            float gv = gp[col];
#pragma unroll
            for (int m = 0; m < 8; ++m) {
#pragma unroll
                for (int i = 0; i < 4; ++i) {
                    int grow = mrow0 + m * 16 + fg * 4 + i;
                    if (grow < M) {
                        float v = (acc[m][n][i] + bv) * gv;
                        outp[(long long)((sh ? 0 : oE) + grow) * Ncols + col] = f2bf(gelu_fast(v));
                    }
                }
            }
        }
    } else {
        if (sh) {
            float sigw = 1.f / (1.f + expf(-swp[0]));
#pragma unroll
            for (int n = 0; n < 4; ++n) {
                int col = col0 + n * 16 + fr;
                float bv = biasS[col];
#pragma unroll
                for (int m = 0; m < 8; ++m) {
#pragma unroll
                    for (int i = 0; i < 4; ++i) {
                        int grow = mrow0 + m * 16 + fg * 4 + i;
                        if (grow < M) {
                            float v = (acc[m][n][i] + bv) * sigw;
                            outS[(long long)grow * DDIM + col] = f2bf(v);
                        }
                    }
                }
            }
        } else {
#pragma unroll
            for (int n = 0; n < 4; ++n) {
                int col = col0 + n * 16 + fr;
                float bv = biasM[z * DDIM + col];
#pragma unroll
                for (int m = 0; m < 8; ++m) {
#pragma unroll
                    for (int i = 0; i < 4; ++i) {
                        int grow = mrow0 + m * 16 + fg * 4 + i;
                        if (grow < M) {
                            int ent = rowtok[oE + grow];
                            float wv = roww[oE + grow];
                            int tok = ent >> 1, slt = ent & 1;
                            float v = (acc[m][n][i] + bv) * wv;
                            outM[((long long)slt * T_TOK + tok) * DDIM + col] = f2bf(v);
                        }
                    }
                }
            }
        }
    }
}

// ---------------- final: y = y0+y1+ysh ; LayerNorm over D ----------------
__global__ void k_ln(const unsigned short* __restrict__ y0,
                     const unsigned short* __restrict__ y1,
                     const unsigned short* __restrict__ ysh,
                     const float* __restrict__ g, const float* __restrict__ b,
                     float* __restrict__ out) {
    const int wid = threadIdx.x >> 6, lane = threadIdx.x & 63;
    const long long t = (long long)blockIdx.x * 4 + wid;
    const long long base = t * DDIM;
    float v[16];
    float s = 0.f, sq = 0.f;
#pragma unroll
    for (int j = 0; j < 2; ++j) {
        int c0 = (lane + 64 * j) * 8;
        uint4 a0 = *(const uint4*)(y0 + base + c0);
        uint4 a1 = *(const uint4*)(y1 + base + c0);
        uint4 a2 = *(const uint4*)(ysh + base + c0);
        const unsigned* u0 = (const unsigned*)&a0;
        const unsigned* u1 = (const unsigned*)&a1;
        const unsigned* u2 = (const unsigned*)&a2;
#pragma unroll
        for (int q = 0; q < 4; ++q) {
            float lo = bf2f((unsigned short)u0[q]) + bf2f((unsigned short)u1[q]) +
                       bf2f((unsigned short)u2[q]);
            float hi = bf2f((unsigned short)(u0[q] >> 16)) + bf2f((unsigned short)(u1[q] >> 16)) +
                       bf2f((unsigned short)(u2[q] >> 16));
            v[j * 8 + q * 2] = lo;
            v[j * 8 + q * 2 + 1] = hi;
            s += lo + hi;
            sq += lo * lo + hi * hi;
        }
    }
#pragma unroll
    for (int off = 32; off; off >>= 1) {
        s += __shfl_xor(s, off);
        sq += __shfl_xor(sq, off);
    }
    const float mean = s * (1.f / DDIM);
    const float var = sq * (1.f / DDIM) - mean * mean;
    const float inv = rsqrtf(var + 1e-5f);
#pragma unroll
    for (int j = 0; j < 2; ++j) {
        int c0 = (lane + 64 * j) * 8;
#pragma unroll
        for (int h = 0; h < 2; ++h) {
            float4 o4;
            float* op = (float*)&o4;
#pragma unroll
            for (int q = 0; q < 4; ++q) {
                int k = h * 4 + q;
                int col = c0 + k;
                op[q] = (v[j * 8 + k] - mean) * inv * g[col] + b[col];
            }
            *(float4*)(out + base + c0 + h * 4) = o4;
        }
    }
}

extern "C" void kernel_launch(void* const* d_in, const int* in_sizes, int n_in,
                              void* d_out, int out_size, void* d_ws, size_t ws_size,
                              hipStream_t stream) {
    const float* x    = (const float*)d_in[0];
    const float* rw   = (const float*)d_in[1];
    const float* rb   = (const float*)d_in[2];
    const float* w1   = (const float*)d_in[3];
    const float* b1   = (const float*)d_in[4];
    const float* gate = (const float*)d_in[5];
    const float* w2   = (const float*)d_in[6];
    const float* b2   = (const float*)d_in[7];
    const float* sw1  = (const float*)d_in[8];
    const float* sb1  = (const float*)d_in[9];
    const float* sgate= (const float*)d_in[10];
    const float* sw2  = (const float*)d_in[11];
    const float* sb2  = (const float*)d_in[12];
    const float* swt  = (const float*)d_in[13];
    const float* lng  = (const float*)d_in[14];
    const float* lnb  = (const float*)d_in[15];
    float* out = (float*)d_out;

    char* p = (char*)d_ws;
    auto take = [&](size_t n) { char* r = p; p += (n + 255) & ~(size_t)255; return r; };
    short* xb   = (short*)take((size_t)T_TOK * DDIM * 2);
    short* w1t  = (short*)take((size_t)NEXP * FDIM * DDIM * 2);
    short* w2t  = (short*)take((size_t)NEXP * DDIM * FDIM * 2);
    short* sw1t = (short*)take((size_t)F2DIM * DDIM * 2);
    short* sw2t = (short*)take((size_t)DDIM * F2DIM * 2);
    short* hbuf = (short*)take((size_t)2 * T_TOK * FDIM * 2);
    short* hs   = (short*)take((size_t)T_TOK * F2DIM * 2);
    unsigned short* ybuf = (unsigned short*)take((size_t)2 * T_TOK * DDIM * 2);
    unsigned short* ysh  = (unsigned short*)take((size_t)T_TOK * DDIM * 2);
    int* eid    = (int*)take((size_t)T_TOK * 2 * 4);
    float* ewt  = (float*)take((size_t)T_TOK * 2 * 4);
    int* rowtok = (int*)take((size_t)2 * T_TOK * 4);
    float* roww = (float*)take((size_t)2 * T_TOK * 4);
    int* cnt    = (int*)take(64);
    int* offs   = (int*)take(64);
    int* cursor = (int*)take(64);

    hipFuncSetAttribute(reinterpret_cast<const void*>(k_fc<1>),
                        hipFuncAttributeMaxDynamicSharedMemorySize, 131072);
    hipFuncSetAttribute(reinterpret_cast<const void*>(k_fc<2>),
                        hipFuncAttributeMaxDynamicSharedMemorySize, 131072);

    hipMemsetAsync(cnt, 0, NEXP * sizeof(int), stream);
    k_router<<<T_TOK / 4, 256, 0, stream>>>(x, rw, rb, eid, ewt, cnt);
    k_scan<<<1, 64, 0, stream>>>(cnt, offs, cursor);
    k_scatter<<<T_TOK / 256, 256, 0, stream>>>(eid, ewt, cursor, rowtok, roww);

    k_cvt<<<2048, 256, 0, stream>>>(x, (unsigned short*)xb, (long long)T_TOK * DDIM / 4);
    // w1 [1024][4096] -> w1t [4096][1024]
    k_tp3<<<dim3(FDIM / 32, DDIM / 64, NEXP), 256, 0, stream>>>(w1, (unsigned short*)w1t, DDIM, FDIM);
    // w2 [4096][1024] -> w2t [1024][4096]
    k_tp3<<<dim3(DDIM / 32, FDIM / 64, NEXP), 256, 0, stream>>>(w2, (unsigned short*)w2t, FDIM, DDIM);
    k_tp3<<<dim3(F2DIM / 32, DDIM / 64, 1), 256, 0, stream>>>(sw1, (unsigned short*)sw1t, DDIM, F2DIM);
    k_tp3<<<dim3(DDIM / 32, F2DIM / 64, 1), 256, 0, stream>>>(sw2, (unsigned short*)sw2t, F2DIM, DDIM);

    // fc1: MoE experts (z<8) + shared (z==8) in one dispatch
    k_fc<1><<<dim3(16, 64, 9), 512, 131072, stream>>>(
        xb, xb, w1t, sw1t, b1, sb1, gate, sgate,
        (unsigned short*)hbuf, (unsigned short*)hs, cnt, offs, rowtok, roww, swt);
    // fc2: MoE (z<8, K=4096) + shared (z==8, K=2048)
    k_fc<2><<<dim3(4, 64, 9), 512, 131072, stream>>>(
        hbuf, hs, w2t, sw2t, b2, sb2, (const float*)nullptr, (const float*)nullptr,
        ybuf, ysh, cnt, offs, rowtok, roww, swt);

    k_ln<<<T_TOK / 4, 256, 0, stream>>>(ybuf, ybuf + (size_t)T_TOK * DDIM, ysh, lng, lnb, out);
}

// Round 5
// 1037.379 us; speedup vs baseline: 1.0983x; 1.0347x over previous
//
#include <hip/hip_runtime.h>
#include <hip/hip_bf16.h>
#include <stdint.h>

typedef __attribute__((ext_vector_type(8))) short bf16x8;
typedef __attribute__((ext_vector_type(4))) float f32x4;
typedef __attribute__((ext_vector_type(4))) unsigned short us4;

#define T_TOK 8192
#define DDIM 1024
#define FDIM 4096
#define F2DIM 2048
#define NEXP 8

#define FENCE() asm volatile("" ::: "memory")
#define BAR() do { FENCE(); __builtin_amdgcn_s_barrier(); FENCE(); } while (0)

__device__ __forceinline__ unsigned short f2bf(float f) {
    unsigned u = __float_as_uint(f);
    u += 0x7fffu + ((u >> 16) & 1u);
    return (unsigned short)(u >> 16);
}
__device__ __forceinline__ float bf2f(unsigned short h) {
    return __uint_as_float(((unsigned)h) << 16);
}
__device__ __forceinline__ float gelu_fast(float v) {
    float u = 0.7978845608028654f * v * (1.0f + 0.044715f * v * v);
    float a = fabsf(u);
    float t = __expf(-2.0f * a);
    float th = (1.0f - t) / (1.0f + t);
    th = u < 0.0f ? -th : th;
    return 0.5f * v * (1.0f + th);
}

// async global->LDS, 16B per lane. LDS dest is wave-uniform base + lane*16.
__device__ __forceinline__ void gl2lds16(const void* g, void* l) {
    __builtin_amdgcn_global_load_lds(
        (const __attribute__((address_space(1))) unsigned int*)(unsigned long long)g,
        (__attribute__((address_space(3))) unsigned int*)(unsigned int)(unsigned long long)l,
        16, 0, 0);
}

// ---------------- router (+ fused f32->bf16 conversion of x) ----------------
__global__ void k_router(const float* __restrict__ x, const float* __restrict__ rw,
                         const float* __restrict__ rb, int* __restrict__ eid,
                         float* __restrict__ ewt, int* __restrict__ cnt,
                         unsigned short* __restrict__ xb) {
    const int wid = threadIdx.x >> 6, lane = threadIdx.x & 63;
    const int t = blockIdx.x * 4 + wid;
    float acc[8];
#pragma unroll
    for (int e = 0; e < 8; ++e) acc[e] = 0.f;
    const float4* xr = (const float4*)(x + (long long)t * DDIM);
#pragma unroll
    for (int c = 0; c < 4; ++c) {
        float4 xv = xr[lane + 64 * c];
        int d0 = (lane + 64 * c) * 4;
        us4 o;
        o.x = f2bf(xv.x); o.y = f2bf(xv.y); o.z = f2bf(xv.z); o.w = f2bf(xv.w);
        *(us4*)(xb + (long long)t * DDIM + d0) = o;
        float xs[4] = {xv.x, xv.y, xv.z, xv.w};
#pragma unroll
        for (int j = 0; j < 4; ++j) {
            const float* wrow = rw + (long long)(d0 + j) * 8;
#pragma unroll
            for (int e = 0; e < 8; ++e) acc[e] += xs[j] * wrow[e];
        }
    }
#pragma unroll
    for (int off = 32; off; off >>= 1)
#pragma unroll
        for (int e = 0; e < 8; ++e) acc[e] += __shfl_xor(acc[e], off);
    if (lane == 0) {
        float lg[8];
#pragma unroll
        for (int e = 0; e < 8; ++e) lg[e] = acc[e] + rb[e];
        int e0 = 0;
#pragma unroll
        for (int e = 1; e < 8; ++e) if (lg[e] > lg[e0]) e0 = e;
        int e1 = -1;
#pragma unroll
        for (int e = 0; e < 8; ++e) {
            if (e == e0) continue;
            if (e1 < 0 || lg[e] > lg[e1]) e1 = e;
        }
        float w0 = 1.f / (1.f + expf(lg[e1] - lg[e0]));
        eid[2 * t] = e0; eid[2 * t + 1] = e1;
        ewt[2 * t] = w0; ewt[2 * t + 1] = 1.f - w0;
        atomicAdd(&cnt[e0], 1);
        atomicAdd(&cnt[e1], 1);
    }
}

__global__ void k_scan(const int* __restrict__ cnt, int* __restrict__ offs,
                       int* __restrict__ cursor) {
    if (threadIdx.x == 0) {
        int s = 0;
        for (int e = 0; e < NEXP; ++e) { offs[e] = s; cursor[e] = s; s += cnt[e]; }
        offs[NEXP] = s;
    }
}

__global__ void k_scatter(const int* __restrict__ eid, const float* __restrict__ ewt,
                          int* __restrict__ cursor, int* __restrict__ rowtok,
                          float* __restrict__ roww) {
    int t = blockIdx.x * blockDim.x + threadIdx.x;
#pragma unroll
    for (int k = 0; k < 2; ++k) {
        int e = eid[2 * t + k];
        int p = atomicAdd(&cursor[e], 1);
        rowtok[p] = (t << 1) | k;
        roww[p] = ewt[2 * t + k];
    }
}

// ------- transpose+convert: in [R][C] f32 -> out [C][R] bf16, 64r x 32c tiles --
__global__ void k_tp3(const float* __restrict__ in, unsigned short* __restrict__ out,
                      int R, int C) {
    const long long base = (long long)blockIdx.z * R * C;
    __shared__ unsigned short ts[32][80];
    const int c0 = blockIdx.x * 32, r0 = blockIdx.y * 64;
    const int t = threadIdx.x;
#pragma unroll
    for (int i = 0; i < 2; ++i) {
        int idx = t + i * 256;
        int row = idx >> 3, c4 = idx & 7;
        float4 v = *(const float4*)(in + base + (long long)(r0 + row) * C + c0 + c4 * 4);
        ts[c4 * 4 + 0][row] = f2bf(v.x);
        ts[c4 * 4 + 1][row] = f2bf(v.y);
        ts[c4 * 4 + 2][row] = f2bf(v.z);
        ts[c4 * 4 + 3][row] = f2bf(v.w);
    }
    __syncthreads();
    int c = t >> 3, r8 = t & 7;
    uint4 o = *(const uint4*)&ts[c][r8 * 8];
    *(uint4*)(out + base + (long long)(c0 + c) * R + r0 + r8 * 8) = o;
}

// ---------------- grouped GEMM: 256x256 tile, fine 16-MFMA phases ----------------
// BK=32 slabs, 4 rotating LDS regions/operand (128KB). 512 thr = 8 waves (2Mx4N),
// wave tile 128x64. Slab i = two phases:
//  phA: read B(n0-3)+A(m0-3), stage slab i+3 A-half, bar, lgkm0, 16 MFMA, bar
//  phB: read A(m4-7), stage slab i+3 B-half, vmcnt(8|4|0), bar, lgkm0, 16 MFMA, bar
// Ledger: when stg (i<=nk-4), after STAGE_B outstanding = slabs i+1..i+3 (12 loads);
// vmcnt(8) completes the 4 oldest = slab i+1 fully landed one slab before its reads.
// Tail: i==nk-3 -> 8 outstanding, vmcnt(4) verifies slab i+1; i==nk-2 -> vmcnt(0).
template <int FC>
__launch_bounds__(512, 2)
__global__ void k_fc(const short* __restrict__ Amoe, const short* __restrict__ Ash,
                     const short* __restrict__ Bmoe, const short* __restrict__ Bsh,
                     const float* __restrict__ biasM, const float* __restrict__ biasS,
                     const float* __restrict__ gateM, const float* __restrict__ gateS,
                     unsigned short* __restrict__ outM, unsigned short* __restrict__ outS,
                     const int* __restrict__ cnt, const int* __restrict__ offs,
                     const int* __restrict__ rowtok, const float* __restrict__ roww,
                     const float* __restrict__ swp) {
    const int z = blockIdx.z;
    const bool sh = (z == 8);
    const int Kd = (FC == 1) ? 1024 : (sh ? 2048 : 4096);
    const int Ncols = (FC == 1) ? (sh ? 2048 : 4096) : 1024;
    const int M = sh ? T_TOK : cnt[z];
    const int oE = sh ? 0 : offs[z];
    const int tm = blockIdx.y, tn = blockIdx.x;
    if (tm * 256 >= M || tn * 256 >= Ncols) return;

    const short* A = sh ? Ash : Amoe;
    const short* B = sh ? Bsh
                        : Bmoe + (long long)z * ((FC == 1) ? (long long)FDIM * DDIM
                                                           : (long long)DDIM * FDIM);

    extern __shared__ short smem[];
    short* const as_base = smem;            // 4 regions x 8192 shorts (16KB each)
    short* const bs_base = smem + 32768;

    const int tid = threadIdx.x, w = tid >> 6, lane = tid & 63;
    const int fr = lane & 15, fg = lane >> 4;
    const int wr = w >> 2, wc = w & 3;

    const short *agp0, *agp1, *bgp0, *bgp1;
    {
        int id = tid, row = id >> 2;
        int gc = (id & 3) ^ ((row >> 1) & 3);
        int r = tm * 256 + row; if (r > M - 1) r = M - 1;
        long long rowix = (FC == 1) ? (sh ? (long long)r : (long long)(rowtok[oE + r] >> 1))
                                    : (sh ? (long long)r : (long long)(oE + r));
        agp0 = A + rowix * (long long)Kd + gc * 8;
        bgp0 = B + (long long)(tn * 256 + row) * Kd + gc * 8;
    }
    {
        int id = tid + 512, row = id >> 2;
        int gc = (id & 3) ^ ((row >> 1) & 3);
        int r = tm * 256 + row; if (r > M - 1) r = M - 1;
        long long rowix = (FC == 1) ? (sh ? (long long)r : (long long)(rowtok[oE + r] >> 1))
                                    : (sh ? (long long)r : (long long)(oE + r));
        agp1 = A + rowix * (long long)Kd + gc * 8;
        bgp1 = B + (long long)(tn * 256 + row) * Kd + gc * 8;
    }
    const int aofs0 = (w * 64) * 8, aofs1 = (512 + w * 64) * 8;  // shorts

    int sa = 0, sb = 0;
    auto STAGE_A = [&]() {
        short* ar = as_base + (sa & 3) * 8192;
        gl2lds16(agp0, ar + aofs0);
        gl2lds16(agp1, ar + aofs1);
        agp0 += 32; agp1 += 32; ++sa;
    };
    auto STAGE_B = [&]() {
        short* br = bs_base + (sb & 3) * 8192;
        gl2lds16(bgp0, br + aofs0);
        gl2lds16(bgp1, br + aofs1);
        bgp0 += 32; bgp1 += 32; ++sb;
    };

    f32x4 acc[8][4];
#pragma unroll
    for (int m = 0; m < 8; ++m)
#pragma unroll
        for (int n = 0; n < 4; ++n)
            acc[m][n] = (f32x4){0.f, 0.f, 0.f, 0.f};

    const int slot = fg ^ ((fr >> 1) & 3);
    const int arow0 = wr * 128 + fr;
    const int brow0 = wc * 64 + fr;
    const int nk = Kd / 32;

    // prologue: stage slabs 0,1,2 (12 loads); slab 0 verified landed
    STAGE_A(); STAGE_B(); STAGE_A(); STAGE_B(); STAGE_A(); STAGE_B();
    asm volatile("s_waitcnt vmcnt(8)" ::: "memory");
    BAR();

    for (int i = 0; i < nk; ++i) {
        const short* Ar = as_base + (i & 3) * 8192;
        const short* Br = bs_base + (i & 3) * 8192;
        const bool stg = (i + 3 < nk);

        // ---- phase A: B frags + A m0-3, 16 MFMA ----
        bf16x8 b[4], xfa[4];
#pragma unroll
        for (int n = 0; n < 4; ++n)
            b[n] = *(const bf16x8*)(Br + (brow0 + n * 16) * 32 + slot * 8);
#pragma unroll
        for (int m = 0; m < 4; ++m)
            xfa[m] = *(const bf16x8*)(Ar + (arow0 + m * 16) * 32 + slot * 8);
        if (stg) STAGE_A();
        BAR();
        asm volatile("s_waitcnt lgkmcnt(0)" ::: "memory");
        __builtin_amdgcn_s_setprio(1);
#pragma unroll
        for (int m = 0; m < 4; ++m)
#pragma unroll
            for (int n = 0; n < 4; ++n)
                acc[m][n] = __builtin_amdgcn_mfma_f32_16x16x32_bf16(xfa[m], b[n], acc[m][n], 0, 0, 0);
        __builtin_amdgcn_s_setprio(0);
        BAR();

        // ---- phase B: A m4-7, 16 MFMA ----
        bf16x8 xfb[4];
#pragma unroll
        for (int m = 0; m < 4; ++m)
            xfb[m] = *(const bf16x8*)(Ar + (arow0 + (m + 4) * 16) * 32 + slot * 8);
        if (stg) {
            STAGE_B();
            asm volatile("s_waitcnt vmcnt(8)" ::: "memory");   // slab i+1 landed
        } else if (i == nk - 3) {
            asm volatile("s_waitcnt vmcnt(4)" ::: "memory");   // slab i+1 landed
        } else if (i == nk - 2) {
            asm volatile("s_waitcnt vmcnt(0)" ::: "memory");   // slab i+1 landed
        }
        BAR();
        asm volatile("s_waitcnt lgkmcnt(0)" ::: "memory");
        __builtin_amdgcn_s_setprio(1);
#pragma unroll
        for (int m = 0; m < 4; ++m)
#pragma unroll
            for (int n = 0; n < 4; ++n)
                acc[m + 4][n] = __builtin_amdgcn_mfma_f32_16x16x32_bf16(xfb[m], b[n], acc[m + 4][n], 0, 0, 0);
        __builtin_amdgcn_s_setprio(0);
        BAR();
    }

    // ---- epilogue. C/D layout: col=lane&15, row=(lane>>4)*4+i ----
    const int mrow0 = tm * 256 + wr * 128;
    const int col0 = tn * 256 + wc * 64;

    if (FC == 1) {
        const float* bp = sh ? biasS : biasM + (long long)z * FDIM;
        const float* gp = sh ? gateS : gateM + (long long)z * FDIM;
        unsigned short* outp = sh ? outS : outM;
#pragma unroll
        for (int n = 0; n < 4; ++n) {
            int col = col0 + n * 16 + fr;
            float bv = bp[col];
            float gv = gp[col];
#pragma unroll
            for (int m = 0; m < 8; ++m) {
#pragma unroll
                for (int i = 0; i < 4; ++i) {
                    int grow = mrow0 + m * 16 + fg * 4 + i;
                    if (grow < M) {
                        float v = (acc[m][n][i] + bv) * gv;
                        outp[(long long)((sh ? 0 : oE) + grow) * Ncols + col] = f2bf(gelu_fast(v));
                    }
                }
            }
        }
    } else {
        if (sh) {
            float sigw = 1.f / (1.f + expf(-swp[0]));
#pragma unroll
            for (int n = 0; n < 4; ++n) {
                int col = col0 + n * 16 + fr;
                float bv = biasS[col];
#pragma unroll
                for (int m = 0; m < 8; ++m) {
#pragma unroll
                    for (int i = 0; i < 4; ++i) {
                        int grow = mrow0 + m * 16 + fg * 4 + i;
                        if (grow < M) {
                            float v = (acc[m][n][i] + bv) * sigw;
                            outS[(long long)grow * DDIM + col] = f2bf(v);
                        }
                    }
                }
            }
        } else {
#pragma unroll
            for (int n = 0; n < 4; ++n) {
                int col = col0 + n * 16 + fr;
                float bv = biasM[z * DDIM + col];
#pragma unroll
                for (int m = 0; m < 8; ++m) {
#pragma unroll
                    for (int i = 0; i < 4; ++i) {
                        int grow = mrow0 + m * 16 + fg * 4 + i;
                        if (grow < M) {
                            int ent = rowtok[oE + grow];
                            float wv = roww[oE + grow];
                            int tok = ent >> 1, slt = ent & 1;
                            float v = (acc[m][n][i] + bv) * wv;
                            outM[((long long)slt * T_TOK + tok) * DDIM + col] = f2bf(v);
                        }
                    }
                }
            }
        }
    }
}

// ---------------- final: y = y0+y1+ysh ; LayerNorm over D ----------------
__global__ void k_ln(const unsigned short* __restrict__ y0,
                     const unsigned short* __restrict__ y1,
                     const unsigned short* __restrict__ ysh,
                     const float* __restrict__ g, const float* __restrict__ b,
                     float* __restrict__ out) {
    const int wid = threadIdx.x >> 6, lane = threadIdx.x & 63;
    const long long t = (long long)blockIdx.x * 4 + wid;
    const long long base = t * DDIM;
    float v[16];
    float s = 0.f, sq = 0.f;
#pragma unroll
    for (int j = 0; j < 2; ++j) {
        int c0 = (lane + 64 * j) * 8;
        uint4 a0 = *(const uint4*)(y0 + base + c0);
        uint4 a1 = *(const uint4*)(y1 + base + c0);
        uint4 a2 = *(const uint4*)(ysh + base + c0);
        const unsigned* u0 = (const unsigned*)&a0;
        const unsigned* u1 = (const unsigned*)&a1;
        const unsigned* u2 = (const unsigned*)&a2;
#pragma unroll
        for (int q = 0; q < 4; ++q) {
            float lo = bf2f((unsigned short)u0[q]) + bf2f((unsigned short)u1[q]) +
                       bf2f((unsigned short)u2[q]);
            float hi = bf2f((unsigned short)(u0[q] >> 16)) + bf2f((unsigned short)(u1[q] >> 16)) +
                       bf2f((unsigned short)(u2[q] >> 16));
            v[j * 8 + q * 2] = lo;
            v[j * 8 + q * 2 + 1] = hi;
            s += lo + hi;
            sq += lo * lo + hi * hi;
        }
    }
#pragma unroll
    for (int off = 32; off; off >>= 1) {
        s += __shfl_xor(s, off);
        sq += __shfl_xor(sq, off);
    }
    const float mean = s * (1.f / DDIM);
    const float var = sq * (1.f / DDIM) - mean * mean;
    const float inv = rsqrtf(var + 1e-5f);
#pragma unroll
    for (int j = 0; j < 2; ++j) {
        int c0 = (lane + 64 * j) * 8;
#pragma unroll
        for (int h = 0; h < 2; ++h) {
            float4 o4;
            float* op = (float*)&o4;
#pragma unroll
            for (int q = 0; q < 4; ++q) {
                int k = h * 4 + q;
                int col = c0 + k;
                op[q] = (v[j * 8 + k] - mean) * inv * g[col] + b[col];
            }
            *(float4*)(out + base + c0 + h * 4) = o4;
        }
    }
}

extern "C" void kernel_launch(void* const* d_in, const int* in_sizes, int n_in,
                              void* d_out, int out_size, void* d_ws, size_t ws_size,
                              hipStream_t stream) {
    const float* x    = (const float*)d_in[0];
    const float* rw   = (const float*)d_in[1];
    const float* rb   = (const float*)d_in[2];
    const float* w1   = (const float*)d_in[3];
    const float* b1   = (const float*)d_in[4];
    const float* gate = (const float*)d_in[5];
    const float* w2   = (const float*)d_in[6];
    const float* b2   = (const float*)d_in[7];
    const float* sw1  = (const float*)d_in[8];
    const float* sb1  = (const float*)d_in[9];
    const float* sgate= (const float*)d_in[10];
    const float* sw2  = (const float*)d_in[11];
    const float* sb2  = (const float*)d_in[12];
    const float* swt  = (const float*)d_in[13];
    const float* lng  = (const float*)d_in[14];
    const float* lnb  = (const float*)d_in[15];
    float* out = (float*)d_out;

    char* p = (char*)d_ws;
    auto take = [&](size_t n) { char* r = p; p += (n + 255) & ~(size_t)255; return r; };
    short* xb   = (short*)take((size_t)T_TOK * DDIM * 2);
    short* w1t  = (short*)take((size_t)NEXP * FDIM * DDIM * 2);
    short* w2t  = (short*)take((size_t)NEXP * DDIM * FDIM * 2);
    short* sw1t = (short*)take((size_t)F2DIM * DDIM * 2);
    short* sw2t = (short*)take((size_t)DDIM * F2DIM * 2);
    short* hbuf = (short*)take((size_t)2 * T_TOK * FDIM * 2);
    short* hs   = (short*)take((size_t)T_TOK * F2DIM * 2);
    unsigned short* ybuf = (unsigned short*)take((size_t)2 * T_TOK * DDIM * 2);
    unsigned short* ysh  = (unsigned short*)take((size_t)T_TOK * DDIM * 2);
    int* eid    = (int*)take((size_t)T_TOK * 2 * 4);
    float* ewt  = (float*)take((size_t)T_TOK * 2 * 4);
    int* rowtok = (int*)take((size_t)2 * T_TOK * 4);
    float* roww = (float*)take((size_t)2 * T_TOK * 4);
    int* cnt    = (int*)take(64);
    int* offs   = (int*)take(64);
    int* cursor = (int*)take(64);

    hipFuncSetAttribute(reinterpret_cast<const void*>(k_fc<1>),
                        hipFuncAttributeMaxDynamicSharedMemorySize, 131072);
    hipFuncSetAttribute(reinterpret_cast<const void*>(k_fc<2>),
                        hipFuncAttributeMaxDynamicSharedMemorySize, 131072);

    hipMemsetAsync(cnt, 0, NEXP * sizeof(int), stream);
    k_router<<<T_TOK / 4, 256, 0, stream>>>(x, rw, rb, eid, ewt, cnt, (unsigned short*)xb);
    k_scan<<<1, 64, 0, stream>>>(cnt, offs, cursor);
    k_scatter<<<T_TOK / 256, 256, 0, stream>>>(eid, ewt, cursor, rowtok, roww);

    k_tp3<<<dim3(FDIM / 32, DDIM / 64, NEXP), 256, 0, stream>>>(w1, (unsigned short*)w1t, DDIM, FDIM);
    k_tp3<<<dim3(DDIM / 32, FDIM / 64, NEXP), 256, 0, stream>>>(w2, (unsigned short*)w2t, FDIM, DDIM);
    k_tp3<<<dim3(F2DIM / 32, DDIM / 64, 1), 256, 0, stream>>>(sw1, (unsigned short*)sw1t, DDIM, F2DIM);
    k_tp3<<<dim3(DDIM / 32, F2DIM / 64, 1), 256, 0, stream>>>(sw2, (unsigned short*)sw2t, F2DIM, DDIM);

    // fc1: MoE experts (z<8, K=1024) + shared (z==8, K=1024).
    // y=32: shared expert M=8192 and worst-case MoE cnt=8192 both need 32 blocks.
    k_fc<1><<<dim3(16, 32, 9), 512, 131072, stream>>>(
        xb, xb, w1t, sw1t, b1, sb1, gate, sgate,
        (unsigned short*)hbuf, (unsigned short*)hs, cnt, offs, rowtok, roww, swt);
    // fc2: MoE (z<8, K=4096) + shared (z==8, K=2048)
    k_fc<2><<<dim3(4, 32, 9), 512, 131072, stream>>>(
        hbuf, hs, w2t, sw2t, b2, sb2, (const float*)nullptr, (const float*)nullptr,
        ybuf, ysh, cnt, offs, rowtok, roww, swt);

    k_ln<<<T_TOK / 4, 256, 0, stream>>>(ybuf, ybuf + (size_t)T_TOK * DDIM, ysh, lng, lnb, out);
}

// Round 6
// 859.436 us; speedup vs baseline: 1.3257x; 1.2070x over previous
//
#include <hip/hip_runtime.h>
#include <hip/hip_bf16.h>
#include <stdint.h>

typedef __attribute__((ext_vector_type(8))) short bf16x8;
typedef __attribute__((ext_vector_type(4))) float f32x4;
typedef __attribute__((ext_vector_type(4))) unsigned short us4;

#define T_TOK 8192
#define DDIM 1024
#define FDIM 4096
#define F2DIM 2048
#define NEXP 8

__device__ __forceinline__ unsigned short f2bf(float f) {
    unsigned u = __float_as_uint(f);
    u += 0x7fffu + ((u >> 16) & 1u);
    return (unsigned short)(u >> 16);
}
__device__ __forceinline__ float bf2f(unsigned short h) {
    return __uint_as_float(((unsigned)h) << 16);
}
__device__ __forceinline__ float gelu_fast(float v) {
    float u = 0.7978845608028654f * v * (1.0f + 0.044715f * v * v);
    float a = fabsf(u);
    float t = __expf(-2.0f * a);
    float th = (1.0f - t) / (1.0f + t);
    th = u < 0.0f ? -th : th;
    return 0.5f * v * (1.0f + th);
}

// async global->LDS, 16B per lane. LDS dest is wave-uniform base + lane*16.
__device__ __forceinline__ void gl2lds16(const void* g, void* l) {
    __builtin_amdgcn_global_load_lds(
        (const __attribute__((address_space(1))) unsigned int*)(unsigned long long)g,
        (__attribute__((address_space(3))) unsigned int*)(unsigned int)(unsigned long long)l,
        16, 0, 0);
}

// ---------------- router (+ fused f32->bf16 conversion of x) ----------------
__global__ void k_router(const float* __restrict__ x, const float* __restrict__ rw,
                         const float* __restrict__ rb, int* __restrict__ eid,
                         float* __restrict__ ewt, int* __restrict__ cnt,
                         unsigned short* __restrict__ xb) {
    const int wid = threadIdx.x >> 6, lane = threadIdx.x & 63;
    const int t = blockIdx.x * 4 + wid;
    float acc[8];
#pragma unroll
    for (int e = 0; e < 8; ++e) acc[e] = 0.f;
    const float4* xr = (const float4*)(x + (long long)t * DDIM);
#pragma unroll
    for (int c = 0; c < 4; ++c) {
        float4 xv = xr[lane + 64 * c];
        int d0 = (lane + 64 * c) * 4;
        us4 o;
        o.x = f2bf(xv.x); o.y = f2bf(xv.y); o.z = f2bf(xv.z); o.w = f2bf(xv.w);
        *(us4*)(xb + (long long)t * DDIM + d0) = o;
        float xs[4] = {xv.x, xv.y, xv.z, xv.w};
#pragma unroll
        for (int j = 0; j < 4; ++j) {
            const float* wrow = rw + (long long)(d0 + j) * 8;
#pragma unroll
            for (int e = 0; e < 8; ++e) acc[e] += xs[j] * wrow[e];
        }
    }
#pragma unroll
    for (int off = 32; off; off >>= 1)
#pragma unroll
        for (int e = 0; e < 8; ++e) acc[e] += __shfl_xor(acc[e], off);
    if (lane == 0) {
        float lg[8];
#pragma unroll
        for (int e = 0; e < 8; ++e) lg[e] = acc[e] + rb[e];
        int e0 = 0;
#pragma unroll
        for (int e = 1; e < 8; ++e) if (lg[e] > lg[e0]) e0 = e;
        int e1 = -1;
#pragma unroll
        for (int e = 0; e < 8; ++e) {
            if (e == e0) continue;
            if (e1 < 0 || lg[e] > lg[e1]) e1 = e;
        }
        float w0 = 1.f / (1.f + expf(lg[e1] - lg[e0]));
        eid[2 * t] = e0; eid[2 * t + 1] = e1;
        ewt[2 * t] = w0; ewt[2 * t + 1] = 1.f - w0;
        atomicAdd(&cnt[e0], 1);
        atomicAdd(&cnt[e1], 1);
    }
}

__global__ void k_scan(const int* __restrict__ cnt, int* __restrict__ offs,
                       int* __restrict__ cursor) {
    if (threadIdx.x == 0) {
        int s = 0;
        for (int e = 0; e < NEXP; ++e) { offs[e] = s; cursor[e] = s; s += cnt[e]; }
        offs[NEXP] = s;
    }
}

__global__ void k_scatter(const int* __restrict__ eid, const float* __restrict__ ewt,
                          int* __restrict__ cursor, int* __restrict__ rowtok,
                          float* __restrict__ roww, int* __restrict__ pos) {
    int t = blockIdx.x * blockDim.x + threadIdx.x;
#pragma unroll
    for (int k = 0; k < 2; ++k) {
        int e = eid[2 * t + k];
        int p = atomicAdd(&cursor[e], 1);
        rowtok[p] = (t << 1) | k;
        roww[p] = ewt[2 * t + k];
        pos[2 * t + k] = p;
    }
}

// ------- transpose+convert: in [R][C] f32 -> out [C][R] bf16, 64r x 32c tiles --
__global__ void k_tp3(const float* __restrict__ in, unsigned short* __restrict__ out,
                      int R, int C) {
    const long long base = (long long)blockIdx.z * R * C;
    __shared__ unsigned short ts[32][80];
    const int c0 = blockIdx.x * 32, r0 = blockIdx.y * 64;
    const int t = threadIdx.x;
#pragma unroll
    for (int i = 0; i < 2; ++i) {
        int idx = t + i * 256;
        int row = idx >> 3, c4 = idx & 7;
        float4 v = *(const float4*)(in + base + (long long)(r0 + row) * C + c0 + c4 * 4);
        ts[c4 * 4 + 0][row] = f2bf(v.x);
        ts[c4 * 4 + 1][row] = f2bf(v.y);
        ts[c4 * 4 + 2][row] = f2bf(v.z);
        ts[c4 * 4 + 3][row] = f2bf(v.w);
    }
    __syncthreads();
    int c = t >> 3, r8 = t & 7;
    uint4 o = *(const uint4*)&ts[c][r8 * 8];
    *(uint4*)(out + base + (long long)(c0 + c) * R + r0 + r8 * 8) = o;
}

// ---------------- grouped GEMM: m97 128x128 structure, panel-ordered 1D grid ---
// 4 waves (2Mx2N), wave tile 64x64, BK=32 single-buffered 16KB LDS, XOR-swizzled.
// Tiles ordered (z, cb, rb) -- rb fastest => B-panel reuse is temporally local --
// then m204-bijective XCD chunk swizzle. z<8 = MoE expert, z==8 = shared.
template <int FC>
__launch_bounds__(256, 4)
__global__ void k_fc(const short* __restrict__ Amoe, const short* __restrict__ Ash,
                     const short* __restrict__ Bmoe, const short* __restrict__ Bsh,
                     const float* __restrict__ biasM, const float* __restrict__ biasS,
                     const float* __restrict__ gateM, const float* __restrict__ gateS,
                     unsigned short* __restrict__ outM, unsigned short* __restrict__ outS,
                     const int* __restrict__ cnt, const int* __restrict__ offs,
                     const int* __restrict__ rowtok, const float* __restrict__ roww,
                     const float* __restrict__ swp) {
    // ---- tile decode: T, swizzle, (z, cb, rb) ----
    int RBz[9];
    int T = 0;
#pragma unroll
    for (int zz = 0; zz < 9; ++zz) {
        int Mz = (zz < 8) ? cnt[zz] : T_TOK;
        int rbn = (Mz + 127) >> 7;
        int cbn = (FC == 1) ? ((zz < 8) ? 32 : 16) : 8;
        RBz[zz] = rbn;
        T += rbn * cbn;
    }
    const int ell = blockIdx.x;
    if (ell >= T) return;
    const int q = T >> 3, r = T & 7;
    const int xk = ell & 7, jj = ell >> 3;
    int t = (xk < r ? xk * (q + 1) : r * (q + 1) + (xk - r) * q) + jj;

    int z = 0, local = t;
    for (; z < 9; ++z) {
        int cbn = (FC == 1) ? ((z < 8) ? 32 : 16) : 8;
        int tz = RBz[z] * cbn;
        if (local < tz) break;
        local -= tz;
    }
    const int RB = RBz[z];
    const int cb = local / RB;
    const int rb = local - cb * RB;

    const bool sh = (z == 8);
    const int Kd = (FC == 1) ? 1024 : (sh ? 2048 : 4096);
    const int Ncols = (FC == 1) ? (sh ? 2048 : 4096) : 1024;
    const int M = sh ? T_TOK : cnt[z];
    const int oE = sh ? 0 : offs[z];

    const short* A = sh ? Ash : Amoe;
    const short* B = sh ? Bsh
                        : Bmoe + (long long)z * ((FC == 1) ? (long long)FDIM * DDIM
                                                           : (long long)DDIM * FDIM);

    __shared__ short As[128][32];
    __shared__ short Bs[128][32];

    const int tid = threadIdx.x, w = tid >> 6, lane = tid & 63;
    const int fr = lane & 15, fg = lane >> 4;
    const int wr = w >> 1, wc = w & 1;

    // staging: 512 chunks of 16B per operand; chunk id: row=id>>2, c=id&3,
    // source pre-swizzle gc = c ^ ((row>>1)&3); LDS dest linear by id.
    const short *ag0, *ag1, *bg0, *bg1;
    {
        int id = tid, row = id >> 2;
        int gc = (id & 3) ^ ((row >> 1) & 3);
        int rA = rb * 128 + row; if (rA > M - 1) rA = M - 1;
        long long rowix;
        if (FC == 1) rowix = sh ? (long long)rA : (long long)(rowtok[oE + rA] >> 1);
        else         rowix = sh ? (long long)rA : (long long)(oE + rA);
        ag0 = A + rowix * (long long)Kd + gc * 8;
        bg0 = B + (long long)(cb * 128 + row) * Kd + gc * 8;
    }
    {
        int id = tid + 256, row = id >> 2;
        int gc = (id & 3) ^ ((row >> 1) & 3);
        int rA = rb * 128 + row; if (rA > M - 1) rA = M - 1;
        long long rowix;
        if (FC == 1) rowix = sh ? (long long)rA : (long long)(rowtok[oE + rA] >> 1);
        else         rowix = sh ? (long long)rA : (long long)(oE + rA);
        ag1 = A + rowix * (long long)Kd + gc * 8;
        bg1 = B + (long long)(cb * 128 + row) * Kd + gc * 8;
    }
    short* const asb0 = &As[0][0] + (w * 64) * 8;
    short* const asb1 = &As[0][0] + (256 + w * 64) * 8;
    short* const bsb0 = &Bs[0][0] + (w * 64) * 8;
    short* const bsb1 = &Bs[0][0] + (256 + w * 64) * 8;

    f32x4 acc[4][4];
#pragma unroll
    for (int m = 0; m < 4; ++m)
#pragma unroll
        for (int n = 0; n < 4; ++n)
            acc[m][n] = (f32x4){0.f, 0.f, 0.f, 0.f};

    const int slot = fg ^ ((fr >> 1) & 3);
    const int arow0 = wr * 64 + fr;
    const int brow0 = wc * 64 + fr;
    const int nk = Kd / 32;

    for (int kt = 0; kt < nk; ++kt) {
        gl2lds16(ag0, asb0); gl2lds16(ag1, asb1);
        gl2lds16(bg0, bsb0); gl2lds16(bg1, bsb1);
        ag0 += 32; ag1 += 32; bg0 += 32; bg1 += 32;
        __syncthreads();

        bf16x8 a[4], b[4];
#pragma unroll
        for (int m = 0; m < 4; ++m)
            a[m] = *(const bf16x8*)(&As[0][0] + (arow0 + m * 16) * 32 + slot * 8);
#pragma unroll
        for (int n = 0; n < 4; ++n)
            b[n] = *(const bf16x8*)(&Bs[0][0] + (brow0 + n * 16) * 32 + slot * 8);
#pragma unroll
        for (int m = 0; m < 4; ++m)
#pragma unroll
            for (int n = 0; n < 4; ++n)
                acc[m][n] = __builtin_amdgcn_mfma_f32_16x16x32_bf16(a[m], b[n], acc[m][n], 0, 0, 0);
        __syncthreads();
    }

    // ---- epilogue. C/D layout: col=lane&15, row=(lane>>4)*4+i. n-innermost. ----
    const int mrow0 = rb * 128 + wr * 64;
    const int col0 = cb * 128 + wc * 64;

    if (FC == 1) {
        const float* bp = sh ? biasS : biasM + (long long)z * FDIM;
        const float* gp = sh ? gateS : gateM + (long long)z * FDIM;
        unsigned short* outp = sh ? outS : outM;
        const long long obase = sh ? 0 : (long long)oE;
        float bv[4], gv[4]; int coln[4];
#pragma unroll
        for (int n = 0; n < 4; ++n) {
            coln[n] = col0 + n * 16 + fr;
            bv[n] = bp[coln[n]];
            gv[n] = gp[coln[n]];
        }
#pragma unroll
        for (int m = 0; m < 4; ++m) {
#pragma unroll
            for (int i = 0; i < 4; ++i) {
                int grow = mrow0 + m * 16 + fg * 4 + i;
                if (grow < M) {
                    unsigned short* rowp = outp + (obase + grow) * (long long)Ncols;
#pragma unroll
                    for (int n = 0; n < 4; ++n) {
                        float v = (acc[m][n][i] + bv[n]) * gv[n];
                        rowp[coln[n]] = f2bf(gelu_fast(v));
                    }
                }
            }
        }
    } else {
        float bv[4]; int coln[4];
        const float* bp = sh ? biasS : biasM + (long long)z * DDIM;
#pragma unroll
        for (int n = 0; n < 4; ++n) {
            coln[n] = col0 + n * 16 + fr;
            bv[n] = bp[coln[n]];
        }
        if (sh) {
            float sigw = 1.f / (1.f + expf(-swp[0]));
#pragma unroll
            for (int m = 0; m < 4; ++m) {
#pragma unroll
                for (int i = 0; i < 4; ++i) {
                    int grow = mrow0 + m * 16 + fg * 4 + i;
                    if (grow < M) {
                        unsigned short* rowp = outS + (long long)grow * DDIM;
#pragma unroll
                        for (int n = 0; n < 4; ++n)
                            rowp[coln[n]] = f2bf((acc[m][n][i] + bv[n]) * sigw);
                    }
                }
            }
        } else {
#pragma unroll
            for (int m = 0; m < 4; ++m) {
#pragma unroll
                for (int i = 0; i < 4; ++i) {
                    int grow = mrow0 + m * 16 + fg * 4 + i;
                    if (grow < M) {
                        int p = oE + grow;
                        float wv = roww[p];
                        unsigned short* rowp = outM + (long long)p * DDIM;   // compact
#pragma unroll
                        for (int n = 0; n < 4; ++n)
                            rowp[coln[n]] = f2bf((acc[m][n][i] + bv[n]) * wv);
                    }
                }
            }
        }
    }
}

// ------- final: y = ycomp[pos0]+ycomp[pos1]+ysh ; LayerNorm over D -------
__global__ void k_ln(const unsigned short* __restrict__ yc,
                     const unsigned short* __restrict__ ysh,
                     const int* __restrict__ pos,
                     const float* __restrict__ g, const float* __restrict__ b,
                     float* __restrict__ out) {
    const int wid = threadIdx.x >> 6, lane = threadIdx.x & 63;
    const long long t = (long long)blockIdx.x * 4 + wid;
    const long long b0 = (long long)pos[2 * t] * DDIM;
    const long long b1 = (long long)pos[2 * t + 1] * DDIM;
    const long long bs = t * DDIM;
    float v[16];
    float s = 0.f, sq = 0.f;
#pragma unroll
    for (int j = 0; j < 2; ++j) {
        int c0 = (lane + 64 * j) * 8;
        uint4 a0 = *(const uint4*)(yc + b0 + c0);
        uint4 a1 = *(const uint4*)(yc + b1 + c0);
        uint4 a2 = *(const uint4*)(ysh + bs + c0);
        const unsigned* u0 = (const unsigned*)&a0;
        const unsigned* u1 = (const unsigned*)&a1;
        const unsigned* u2 = (const unsigned*)&a2;
#pragma unroll
        for (int qq = 0; qq < 4; ++qq) {
            float lo = bf2f((unsigned short)u0[qq]) + bf2f((unsigned short)u1[qq]) +
                       bf2f((unsigned short)u2[qq]);
            float hi = bf2f((unsigned short)(u0[qq] >> 16)) + bf2f((unsigned short)(u1[qq] >> 16)) +
                       bf2f((unsigned short)(u2[qq] >> 16));
            v[j * 8 + qq * 2] = lo;
            v[j * 8 + qq * 2 + 1] = hi;
            s += lo + hi;
            sq += lo * lo + hi * hi;
        }
    }
#pragma unroll
    for (int off = 32; off; off >>= 1) {
        s += __shfl_xor(s, off);
        sq += __shfl_xor(sq, off);
    }
    const float mean = s * (1.f / DDIM);
    const float var = sq * (1.f / DDIM) - mean * mean;
    const float inv = rsqrtf(var + 1e-5f);
#pragma unroll
    for (int j = 0; j < 2; ++j) {
        int c0 = (lane + 64 * j) * 8;
#pragma unroll
        for (int h = 0; h < 2; ++h) {
            float4 o4;
            float* op = (float*)&o4;
#pragma unroll
            for (int qq = 0; qq < 4; ++qq) {
                int k = h * 4 + qq;
                int col = c0 + k;
                op[qq] = (v[j * 8 + k] - mean) * inv * g[col] + b[col];
            }
            *(float4*)(out + bs + c0 + h * 4) = o4;
        }
    }
}

extern "C" void kernel_launch(void* const* d_in, const int* in_sizes, int n_in,
                              void* d_out, int out_size, void* d_ws, size_t ws_size,
                              hipStream_t stream) {
    const float* x    = (const float*)d_in[0];
    const float* rw   = (const float*)d_in[1];
    const float* rb   = (const float*)d_in[2];
    const float* w1   = (const float*)d_in[3];
    const float* b1   = (const float*)d_in[4];
    const float* gate = (const float*)d_in[5];
    const float* w2   = (const float*)d_in[6];
    const float* b2   = (const float*)d_in[7];
    const float* sw1  = (const float*)d_in[8];
    const float* sb1  = (const float*)d_in[9];
    const float* sgate= (const float*)d_in[10];
    const float* sw2  = (const float*)d_in[11];
    const float* sb2  = (const float*)d_in[12];
    const float* swt  = (const float*)d_in[13];
    const float* lng  = (const float*)d_in[14];
    const float* lnb  = (const float*)d_in[15];
    float* out = (float*)d_out;

    char* p = (char*)d_ws;
    auto take = [&](size_t n) { char* r = p; p += (n + 255) & ~(size_t)255; return r; };
    short* xb   = (short*)take((size_t)T_TOK * DDIM * 2);
    short* w1t  = (short*)take((size_t)NEXP * FDIM * DDIM * 2);
    short* w2t  = (short*)take((size_t)NEXP * DDIM * FDIM * 2);
    short* sw1t = (short*)take((size_t)F2DIM * DDIM * 2);
    short* sw2t = (short*)take((size_t)DDIM * F2DIM * 2);
    short* hbuf = (short*)take((size_t)2 * T_TOK * FDIM * 2);
    short* hs   = (short*)take((size_t)T_TOK * F2DIM * 2);
    unsigned short* ycomp = (unsigned short*)take((size_t)2 * T_TOK * DDIM * 2);
    unsigned short* ysh   = (unsigned short*)take((size_t)T_TOK * DDIM * 2);
    int* eid    = (int*)take((size_t)T_TOK * 2 * 4);
    float* ewt  = (float*)take((size_t)T_TOK * 2 * 4);
    int* rowtok = (int*)take((size_t)2 * T_TOK * 4);
    float* roww = (float*)take((size_t)2 * T_TOK * 4);
    int* pos    = (int*)take((size_t)2 * T_TOK * 4);
    int* cnt    = (int*)take(64);
    int* offs   = (int*)take(64);
    int* cursor = (int*)take(64);

    hipMemsetAsync(cnt, 0, NEXP * sizeof(int), stream);
    k_router<<<T_TOK / 4, 256, 0, stream>>>(x, rw, rb, eid, ewt, cnt, (unsigned short*)xb);
    k_scan<<<1, 64, 0, stream>>>(cnt, offs, cursor);
    k_scatter<<<T_TOK / 256, 256, 0, stream>>>(eid, ewt, cursor, rowtok, roww, pos);

    k_tp3<<<dim3(FDIM / 32, DDIM / 64, NEXP), 256, 0, stream>>>(w1, (unsigned short*)w1t, DDIM, FDIM);
    k_tp3<<<dim3(DDIM / 32, FDIM / 64, NEXP), 256, 0, stream>>>(w2, (unsigned short*)w2t, FDIM, DDIM);
    k_tp3<<<dim3(F2DIM / 32, DDIM / 64, 1), 256, 0, stream>>>(sw1, (unsigned short*)sw1t, DDIM, F2DIM);
    k_tp3<<<dim3(DDIM / 32, F2DIM / 64, 1), 256, 0, stream>>>(sw2, (unsigned short*)sw2t, F2DIM, DDIM);

    // fc1: tiles = sum_e ceil(cnt/128)*32 (<= 135*32=4320) + shared 64*16=1024
    k_fc<1><<<5344, 256, 0, stream>>>(
        xb, xb, w1t, sw1t, b1, sb1, gate, sgate,
        (unsigned short*)hbuf, (unsigned short*)hs, cnt, offs, rowtok, roww, swt);
    // fc2: tiles = sum_e ceil(cnt/128)*8 (<= 1080) + shared 64*8=512
    k_fc<2><<<1592, 256, 0, stream>>>(
        hbuf, hs, w2t, sw2t, b2, sb2, (const float*)nullptr, (const float*)nullptr,
        ycomp, ysh, cnt, offs, rowtok, roww, swt);

    k_ln<<<T_TOK / 4, 256, 0, stream>>>(ycomp, ysh, pos, lng, lnb, out);
}